// Round 2
// baseline (591.059 us; speedup 1.0000x reference)
//
#include <hip/hip_runtime.h>
#include <stdint.h>

#define B_ 4
#define S_ 1024
#define HID_ 1024
#define H_ 16
#define DH_ 64
#define NDIST 33
#define SCALE_ 0.125f

typedef unsigned short u16;
typedef __attribute__((ext_vector_type(8))) short short8;
typedef __attribute__((ext_vector_type(4))) float floatx4;

static __device__ __forceinline__ float bf2f(u16 u) {
  union { unsigned int i; float f; } v; v.i = ((unsigned int)u) << 16; return v.f;
}
static __device__ __forceinline__ u16 f2bf(float x) {
  union { float f; unsigned int i; } v; v.f = x;
  return (u16)((v.i + 0x7FFFu + ((v.i >> 16) & 1u)) >> 16);
}
static __device__ __forceinline__ floatx4 mfma_bf16(short8 a, short8 b, floatx4 c) {
  return __builtin_amdgcn_mfma_f32_16x16x32_bf16(a, b, c, 0, 0, 0);
}

// Converted small-tensor element offsets within the conv region (u16 units)
#define OFF_WQ   0
#define OFF_BQ   1048576
#define OFF_WK   1049600
#define OFF_BK   2098176
#define OFF_WV   2099200
#define OFF_BV   3147776
#define OFF_RELK 3148800
#define OFF_RELV 3150912
#define OFF_FCW  3153024
#define OFF_FCB  4201600
#define CONV_TOT 4202624

struct SrcPtrs { const void* p[10]; };

// ---------------------------------------------------------------------------
// Dtype detector: if the input is fp32 read as u16 pairs, the EVEN halves are
// fp32 mantissa bits -> as bf16 they are huge with ~certainty over 8192
// samples. Genuine bf16 N(0,1) data stays < 10. Writes flag: 1 = fp32 inputs.
// ---------------------------------------------------------------------------
__global__ __launch_bounds__(256) void detect_kernel(const u16* __restrict__ q,
                                                     int* __restrict__ flag) {
  __shared__ float red[256];
  float m = 0.f;
  for (int i = threadIdx.x; i < 8192; i += 256) {
    float v = fabsf(bf2f(q[2 * i]));
    if (v < 1e30f) m = fmaxf(m, v);   // skip inf/NaN garbage, keep finite big
    else m = fmaxf(m, 1e20f);
  }
  red[threadIdx.x] = m;
  __syncthreads();
  for (int s = 128; s > 0; s >>= 1) {
    if (threadIdx.x < (unsigned)s) red[threadIdx.x] = fmaxf(red[threadIdx.x], red[threadIdx.x + s]);
    __syncthreads();
  }
  if (threadIdx.x == 0) *flag = (red[0] > 1e4f) ? 1 : 0;
}

// ---------------------------------------------------------------------------
// Convert the 10 weight/bias/rel tensors to bf16 in ws (copy if already bf16).
// Flat grid; constexpr per-segment block table. 256 thr x 4 elems per block.
// ---------------------------------------------------------------------------
__global__ __launch_bounds__(256) void convert_kernel(SrcPtrs srcs,
                                                      const int* __restrict__ flag,
                                                      u16* __restrict__ dst) {
  constexpr int segsz[10] = {1048576,1024,1048576,1024,1048576,1024,2112,2112,1048576,1024};
  constexpr int cumE[10]  = {OFF_WQ,OFF_BQ,OFF_WK,OFF_BK,OFF_WV,OFF_BV,OFF_RELK,OFF_RELV,OFF_FCW,OFF_FCB};
  constexpr int cumB[11]  = {0,1024,1025,2049,2050,3074,3075,3078,3081,4105,4106};
  const int bid = blockIdx.x;
  int t = 0;
  #pragma unroll
  for (int i = 1; i < 10; ++i) if (bid >= cumB[i]) t = i;
  const int chunk = (bid - cumB[t]) * 1024 + threadIdx.x * 4;
  if (chunk >= segsz[t]) return;
  u16 o[4];
  if (*flag) {
    const float* s = (const float*)srcs.p[t];
    float4 v = *(const float4*)(s + chunk);
    o[0] = f2bf(v.x); o[1] = f2bf(v.y); o[2] = f2bf(v.z); o[3] = f2bf(v.w);
  } else {
    const u16* s = (const u16*)srcs.p[t];
    *(uint2*)o = *(const uint2*)(s + chunk);
  }
  *(uint2*)(dst + cumE[t] + chunk) = *(const uint2*)o;
}

// ---------------------------------------------------------------------------
// Q/K/V projection: C[bs, h*64+e] = sum_d A[bs,d] * W[h,d,e] + bias[h,e]
// A raw input (bf16 or fp32 per flag); W/bias from converted bf16 region.
// Output [B, H, S, DH] bf16. grid (64, 16, 3), block 256.
// ---------------------------------------------------------------------------
__global__ __launch_bounds__(256) void proj_kernel(
    const void* __restrict__ qin, const void* __restrict__ kin, const void* __restrict__ vin,
    const u16* __restrict__ conv, const int* __restrict__ flag,
    u16* __restrict__ qo, u16* __restrict__ ko, u16* __restrict__ vo)
{
  const int z = blockIdx.z;
  const void* A   = (z == 0) ? qin : (z == 1) ? kin : vin;
  const u16* W    = conv + ((z == 0) ? OFF_WQ : (z == 1) ? OFF_WK : OFF_WV);
  const u16* bias = conv + ((z == 0) ? OFF_BQ : (z == 1) ? OFF_BK : OFF_BV);
  u16*       O    = (z == 0) ? qo  : (z == 1) ? ko  : vo;

  const int rt  = blockIdx.x;
  const int h   = blockIdx.y;
  const int tid = threadIdx.x;
  const int lane = tid & 63, w = tid >> 6, quad = lane >> 4, l16 = lane & 15;
  const int isf = *flag;

  __shared__ u16 a_lds[64][56];
  __shared__ u16 bt_lds[64][56];

  floatx4 acc0 = {0.f,0.f,0.f,0.f}, acc1 = acc0, acc2 = acc0, acc3 = acc0;
  const int m0 = w * 16;

  for (int kk = 0; kk < HID_ / 32; ++kk) {
    __syncthreads();
    { // stage A tile [64 rows][32 k]
      int row = tid >> 2, c8 = (tid & 3) * 8;
      size_t off = (size_t)(rt * 64 + row) * HID_ + kk * 32 + c8;
      if (isf) {
        const float* Af = (const float*)A;
        float4 v0 = *(const float4*)(Af + off);
        float4 v1 = *(const float4*)(Af + off + 4);
        u16 tmp[8] = {f2bf(v0.x),f2bf(v0.y),f2bf(v0.z),f2bf(v0.w),
                      f2bf(v1.x),f2bf(v1.y),f2bf(v1.z),f2bf(v1.w)};
        *(uint4*)(&a_lds[row][c8]) = *(const uint4*)tmp;
      } else {
        *(uint4*)(&a_lds[row][c8]) = *(const uint4*)((const u16*)A + off);
      }
    }
    { // stage W tile [32 d][64 e] -> bt_lds[e][d]
      int d = tid >> 3, e8 = (tid & 7) * 8;
      uint4 tmp = *(const uint4*)(W + (size_t)h * HID_ * DH_ +
                                  (size_t)(kk * 32 + d) * DH_ + e8);
      const u16* t8 = (const u16*)&tmp;
      #pragma unroll
      for (int i = 0; i < 8; ++i) bt_lds[e8 + i][d] = t8[i];
    }
    __syncthreads();
    short8 a = *(const short8*)(&a_lds[m0 + l16][quad * 8]);
    acc0 = mfma_bf16(a, *(const short8*)(&bt_lds[ 0 + l16][quad * 8]), acc0);
    acc1 = mfma_bf16(a, *(const short8*)(&bt_lds[16 + l16][quad * 8]), acc1);
    acc2 = mfma_bf16(a, *(const short8*)(&bt_lds[32 + l16][quad * 8]), acc2);
    acc3 = mfma_bf16(a, *(const short8*)(&bt_lds[48 + l16][quad * 8]), acc3);
  }

  floatx4 accs[4] = {acc0, acc1, acc2, acc3};
  #pragma unroll
  for (int n = 0; n < 4; ++n) {
    int col = n * 16 + l16;
    float bb = bf2f(bias[h * DH_ + col]);
    #pragma unroll
    for (int r = 0; r < 4; ++r) {
      int m  = m0 + quad * 4 + r;
      int bs = rt * 64 + m;
      int b  = bs >> 10, s = bs & 1023;
      O[(((size_t)(b * H_ + h)) * S_ + s) * DH_ + col] = f2bf(accs[n][r] + bb);
    }
  }
}

// ---------------------------------------------------------------------------
// Fused attention per (b,h,q-tile of 32): streaming over 32 k-tiles of 32.
// grid (32, H, B), block 256 (4 waves).
// ---------------------------------------------------------------------------
__global__ __launch_bounds__(256) void attn_kernel(
    const u16* __restrict__ Q, const u16* __restrict__ K, const u16* __restrict__ V,
    const u16* __restrict__ conv, u16* __restrict__ O)
{
  const u16* relk = conv + OFF_RELK;
  const u16* relv = conv + OFF_RELV;
  const int qt = blockIdx.x, h = blockIdx.y, b = blockIdx.z;
  const int tid = threadIdx.x;
  const int lane = tid & 63, w = tid >> 6, quad = lane >> 4, l16 = lane & 15;
  const size_t base = ((size_t)(b * H_ + h)) * S_ * DH_;

  __shared__ u16 q_lds[32][88];
  __shared__ u16 k_lds[32][88];
  __shared__ u16 vt_lds[64][56];
  __shared__ u16 p_lds[32][56];
  __shared__ float rq_lds[32][NDIST];
  __shared__ float bucket[32][NDIST];
  __shared__ float relk_lds[NDIST][64];
  __shared__ float relv_lds[NDIST][64];
  __shared__ float l_lds[32];

  {
    int row = tid >> 3, e8 = (tid & 7) * 8;
    *(uint4*)(&q_lds[row][e8]) =
        *(const uint4*)(Q + base + (size_t)(qt * 32 + row) * DH_ + e8);
  }
  for (int i = tid; i < NDIST * 64; i += 256) {
    int d = i >> 6, e = i & 63;
    relk_lds[d][e] = bf2f(relk[i]);
    relv_lds[d][e] = bf2f(relv[i]);
  }
  for (int i = tid; i < 32 * NDIST; i += 256) ((float*)bucket)[i] = 0.f;
  __syncthreads();
  for (int i = tid; i < 32 * NDIST; i += 256) {
    int m = i / NDIST, d = i % NDIST;
    float s = 0.f;
    #pragma unroll 8
    for (int e = 0; e < 64; ++e) s += bf2f(q_lds[m][e]) * relk_lds[d][e];
    rq_lds[m][d] = s;
  }

  floatx4 accO0 = {0.f,0.f,0.f,0.f}, accO1 = accO0;
  const int m0 = (w >> 1) * 16, n0 = (w & 1) * 16;

  for (int kt = 0; kt < 32; ++kt) {
    __syncthreads();
    {
      int row = tid >> 3, e8 = (tid & 7) * 8;
      *(uint4*)(&k_lds[row][e8]) =
          *(const uint4*)(K + base + (size_t)(kt * 32 + row) * DH_ + e8);
      uint4 tmp = *(const uint4*)(V + base + (size_t)(kt * 32 + row) * DH_ + e8);
      const u16* t8 = (const u16*)&tmp;
      #pragma unroll
      for (int i = 0; i < 8; ++i) vt_lds[e8 + i][row] = t8[i];
    }
    __syncthreads();

    floatx4 sacc = {0.f,0.f,0.f,0.f};
    sacc = mfma_bf16(*(const short8*)(&q_lds[m0 + l16][quad * 8]),
                     *(const short8*)(&k_lds[n0 + l16][quad * 8]), sacc);
    sacc = mfma_bf16(*(const short8*)(&q_lds[m0 + l16][32 + quad * 8]),
                     *(const short8*)(&k_lds[n0 + l16][32 + quad * 8]), sacc);

    const int dkt = kt - qt;
    float pv[4];
    #pragma unroll
    for (int r = 0; r < 4; ++r) {
      int ml = m0 + quad * 4 + r, nl = n0 + l16;
      int dist = (kt * 32 + nl) - (qt * 32 + ml);
      dist = (dist < -16 ? -16 : (dist > 16 ? 16 : dist)) + 16;
      float tlog = (sacc[r] + rq_lds[ml][dist]) * SCALE_;
      tlog = fminf(tlog, 30.f);          // insurance vs inf
      float p = __expf(tlog);
      pv[r] = p;
      p_lds[ml][nl] = f2bf(p);
    }
    if (dkt >= 2 || dkt <= -2) {
      const int D = (dkt >= 2) ? (NDIST - 1) : 0;
      float s0 = pv[0], s1 = pv[1], s2 = pv[2], s3 = pv[3];
      #pragma unroll
      for (int off = 1; off < 16; off <<= 1) {
        s0 += __shfl_xor(s0, off, 64);
        s1 += __shfl_xor(s1, off, 64);
        s2 += __shfl_xor(s2, off, 64);
        s3 += __shfl_xor(s3, off, 64);
      }
      if (l16 == 0) {
        atomicAdd(&bucket[m0 + quad * 4 + 0][D], s0);
        atomicAdd(&bucket[m0 + quad * 4 + 1][D], s1);
        atomicAdd(&bucket[m0 + quad * 4 + 2][D], s2);
        atomicAdd(&bucket[m0 + quad * 4 + 3][D], s3);
      }
    } else {
      #pragma unroll
      for (int r = 0; r < 4; ++r) {
        int ml = m0 + quad * 4 + r, nl = n0 + l16;
        int dist = (kt * 32 + nl) - (qt * 32 + ml);
        dist = (dist < -16 ? -16 : (dist > 16 ? 16 : dist)) + 16;
        atomicAdd(&bucket[ml][dist], pv[r]);
      }
    }
    __syncthreads();

    {
      short8 pa = *(const short8*)(&p_lds[m0 + l16][quad * 8]);
      int e0 = (w & 1) * 32;
      accO0 = mfma_bf16(pa, *(const short8*)(&vt_lds[e0 + l16][quad * 8]), accO0);
      accO1 = mfma_bf16(pa, *(const short8*)(&vt_lds[e0 + 16 + l16][quad * 8]), accO1);
    }
  }

  __syncthreads();
  if (tid < 32) {
    float s = 0.f;
    #pragma unroll
    for (int d = 0; d < NDIST; ++d) s += bucket[tid][d];
    l_lds[tid] = s;
  }
  __syncthreads();

  floatx4 accs[2] = {accO0, accO1};
  #pragma unroll
  for (int t = 0; t < 2; ++t) {
    int e = (w & 1) * 32 + t * 16 + l16;
    #pragma unroll
    for (int r = 0; r < 4; ++r) {
      int ml = m0 + quad * 4 + r;
      float rvb = 0.f;
      #pragma unroll
      for (int d = 0; d < NDIST; ++d) rvb += bucket[ml][d] * relv_lds[d][e];
      float val = (accs[t][r] + rvb) / l_lds[ml];
      int s = qt * 32 + ml;
      O[(((size_t)(b * S_ + s)) * H_ + h) * DH_ + e] = f2bf(val);
    }
  }
}

// ---------------------------------------------------------------------------
// fc: out[m, j] = sum_i X[m,i] * fc_W[j,i] + fc_b[j]; dual-dtype output store.
// grid (64, 16), block 256.
// ---------------------------------------------------------------------------
__global__ __launch_bounds__(256) void fc_kernel(
    const u16* __restrict__ X, const u16* __restrict__ conv,
    const int* __restrict__ flag, void* __restrict__ outv)
{
  const u16* Wf = conv + OFF_FCW;
  const u16* bf = conv + OFF_FCB;
  const int rt = blockIdx.x, ct = blockIdx.y;
  const int tid = threadIdx.x;
  const int lane = tid & 63, w = tid >> 6, quad = lane >> 4, l16 = lane & 15;
  const int isf = *flag;

  __shared__ u16 a_lds[64][56];
  __shared__ u16 bt_lds[64][56];

  floatx4 acc0 = {0.f,0.f,0.f,0.f}, acc1 = acc0, acc2 = acc0, acc3 = acc0;
  const int m0 = w * 16;

  for (int kk = 0; kk < HID_ / 32; ++kk) {
    __syncthreads();
    {
      int row = tid >> 2, c8 = (tid & 3) * 8;
      *(uint4*)(&a_lds[row][c8]) =
          *(const uint4*)(X + (size_t)(rt * 64 + row) * HID_ + kk * 32 + c8);
      *(uint4*)(&bt_lds[row][c8]) =
          *(const uint4*)(Wf + (size_t)(ct * 64 + row) * HID_ + kk * 32 + c8);
    }
    __syncthreads();
    short8 a = *(const short8*)(&a_lds[m0 + l16][quad * 8]);
    acc0 = mfma_bf16(a, *(const short8*)(&bt_lds[ 0 + l16][quad * 8]), acc0);
    acc1 = mfma_bf16(a, *(const short8*)(&bt_lds[16 + l16][quad * 8]), acc1);
    acc2 = mfma_bf16(a, *(const short8*)(&bt_lds[32 + l16][quad * 8]), acc2);
    acc3 = mfma_bf16(a, *(const short8*)(&bt_lds[48 + l16][quad * 8]), acc3);
  }

  floatx4 accs[4] = {acc0, acc1, acc2, acc3};
  #pragma unroll
  for (int n = 0; n < 4; ++n) {
    int col = ct * 64 + n * 16 + l16;
    float bb = bf2f(bf[col]);
    #pragma unroll
    for (int r = 0; r < 4; ++r) {
      int m = rt * 64 + m0 + quad * 4 + r;
      float val = accs[n][r] + bb;
      size_t idx = (size_t)m * HID_ + col;
      if (isf) ((float*)outv)[idx] = val;
      else     ((u16*)outv)[idx]   = f2bf(val);
    }
  }
}

extern "C" void kernel_launch(void* const* d_in, const int* in_sizes, int n_in,
                              void* d_out, int out_size, void* d_ws, size_t ws_size,
                              hipStream_t stream) {
  int*  flag = (int*)d_ws;
  u16*  conv = (u16*)((char*)d_ws + 16);
  u16*  qw   = conv + CONV_TOT;
  u16*  kw   = qw + (size_t)B_ * H_ * S_ * DH_;
  u16*  vw   = kw + (size_t)B_ * H_ * S_ * DH_;
  u16*  xw   = vw + (size_t)B_ * H_ * S_ * DH_;

  detect_kernel<<<1, 256, 0, stream>>>((const u16*)d_in[0], flag);

  SrcPtrs sp;
  for (int i = 0; i < 10; ++i) sp.p[i] = d_in[3 + i];
  convert_kernel<<<4106, 256, 0, stream>>>(sp, flag, conv);

  proj_kernel<<<dim3(64, 16, 3), 256, 0, stream>>>(d_in[0], d_in[1], d_in[2],
                                                   conv, flag, qw, kw, vw);
  attn_kernel<<<dim3(32, H_, B_), 256, 0, stream>>>(qw, kw, vw, conv, xw);
  fc_kernel<<<dim3(64, 16), 256, 0, stream>>>(xw, conv, flag, d_out);
}

// Round 3
// 362.552 us; speedup vs baseline: 1.6303x; 1.6303x over previous
//
#include <hip/hip_runtime.h>
#include <stdint.h>

#define B_ 4
#define S_ 1024
#define HID_ 1024
#define H_ 16
#define DH_ 64
#define NDIST 33
#define SCALE_ 0.125f

typedef unsigned short u16;
typedef __attribute__((ext_vector_type(8))) short short8;
typedef __attribute__((ext_vector_type(4))) float floatx4;

static __device__ __forceinline__ float bf2f(u16 u) {
  union { unsigned int i; float f; } v; v.i = ((unsigned int)u) << 16; return v.f;
}
static __device__ __forceinline__ u16 f2bf(float x) {
  union { float f; unsigned int i; } v; v.f = x;
  return (u16)((v.i + 0x7FFFu + ((v.i >> 16) & 1u)) >> 16);
}
static __device__ __forceinline__ floatx4 mfma_bf16(short8 a, short8 b, floatx4 c) {
  return __builtin_amdgcn_mfma_f32_16x16x32_bf16(a, b, c, 0, 0, 0);
}

// conv region element offsets (u16 units)
#define OFF_BQ   0
#define OFF_BK   1024
#define OFF_BV   2048
#define OFF_RELK 3072
#define OFF_RELV 5184
#define OFF_FCW  7296
#define OFF_FCB  1055872
#define CONV_TOT 1056896

struct SrcPtrs { const void* p[7]; };

// ---------------------------------------------------------------------------
// Dtype detector: fp32 read as u16 pairs -> even halves are mantissa bits ->
// huge as bf16. flag=1 means fp32 inputs.
// ---------------------------------------------------------------------------
__global__ __launch_bounds__(256) void detect_kernel(const u16* __restrict__ q,
                                                     int* __restrict__ flag) {
  __shared__ float red[256];
  float m = 0.f;
  for (int i = threadIdx.x; i < 8192; i += 256) {
    float v = fabsf(bf2f(q[2 * i]));
    m = fmaxf(m, (v < 1e30f) ? v : 1e20f);
  }
  red[threadIdx.x] = m;
  __syncthreads();
  for (int s = 128; s > 0; s >>= 1) {
    if (threadIdx.x < (unsigned)s) red[threadIdx.x] = fmaxf(red[threadIdx.x], red[threadIdx.x + s]);
    __syncthreads();
  }
  if (threadIdx.x == 0) *flag = (red[0] > 1e4f) ? 1 : 0;
}

// ---------------------------------------------------------------------------
// Convert biases / rel tables / fcW to bf16 (copy if already bf16).
// ---------------------------------------------------------------------------
__global__ __launch_bounds__(256) void convert_kernel(SrcPtrs srcs,
                                                      const int* __restrict__ flag,
                                                      u16* __restrict__ dst) {
  constexpr int segsz[7] = {1024,1024,1024,2112,2112,1048576,1024};
  constexpr int cumE[7]  = {OFF_BQ,OFF_BK,OFF_BV,OFF_RELK,OFF_RELV,OFF_FCW,OFF_FCB};
  constexpr int cumB[8]  = {0,1,2,3,6,9,1033,1034};
  const int bid = blockIdx.x;
  int t = 0;
  #pragma unroll
  for (int i = 1; i < 7; ++i) if (bid >= cumB[i]) t = i;
  const int chunk = (bid - cumB[t]) * 1024 + threadIdx.x * 4;
  if (chunk >= segsz[t]) return;
  __align__(8) u16 o[4];
  if (*flag) {
    const float* s = (const float*)srcs.p[t];
    float4 v = *(const float4*)(s + chunk);
    o[0] = f2bf(v.x); o[1] = f2bf(v.y); o[2] = f2bf(v.z); o[3] = f2bf(v.w);
  } else {
    const u16* s = (const u16*)srcs.p[t];
    *(uint2*)o = *(const uint2*)(s + chunk);
  }
  *(uint2*)(dst + cumE[t] + chunk) = *(const uint2*)o;
}

// ---------------------------------------------------------------------------
// W transpose: raw W [h][d][e] (fp32 or bf16) -> wt[z][h*64+e][d] bf16.
// lane = d mapping + XOR chunk swizzle -> conflict-free LDS scatter.
// grid (16 d-tiles, 16 h, 3 z), block 256.
// ---------------------------------------------------------------------------
__global__ __launch_bounds__(256) void wtrans_kernel(
    const void* __restrict__ Wq, const void* __restrict__ Wk, const void* __restrict__ Wv,
    const int* __restrict__ flag, u16* __restrict__ wt)
{
  const int dt = blockIdx.x, h = blockIdx.y, z = blockIdx.z;
  const void* W = (z == 0) ? Wq : (z == 1) ? Wk : Wv;
  const int tid = threadIdx.x;
  const int isf = *flag;
  __shared__ __align__(16) u16 t_l[64 * 72];

  #pragma unroll
  for (int i = 0; i < 2; ++i) {
    int g = tid + 256 * i;
    int d = g & 63, e8 = (g >> 6) * 8;
    size_t off = ((size_t)h * HID_ + dt * 64 + d) * DH_ + e8;
    __align__(16) u16 tmp[8];
    if (isf) {
      const float* Wf = (const float*)W + off;
      float4 v0 = *(const float4*)Wf;
      float4 v1 = *(const float4*)(Wf + 4);
      tmp[0]=f2bf(v0.x); tmp[1]=f2bf(v0.y); tmp[2]=f2bf(v0.z); tmp[3]=f2bf(v0.w);
      tmp[4]=f2bf(v1.x); tmp[5]=f2bf(v1.y); tmp[6]=f2bf(v1.z); tmp[7]=f2bf(v1.w);
    } else {
      *(uint4*)tmp = *(const uint4*)((const u16*)W + off);
    }
    #pragma unroll
    for (int j = 0; j < 8; ++j) {
      int e = e8 + j;
      t_l[e * 72 + (((d >> 3) ^ (e & 7)) << 3) + (d & 7)] = tmp[j];
    }
  }
  __syncthreads();
  {
    int e = tid >> 2, c0 = (tid & 3) * 2;
    u16* dst = wt + ((size_t)(z * H_ + h) * DH_ + e) * HID_ + dt * 64;
    uint4 x0 = *(const uint4*)(t_l + e * 72 + (((c0    ) ^ (e & 7)) << 3));
    uint4 x1 = *(const uint4*)(t_l + e * 72 + (((c0 + 1) ^ (e & 7)) << 3));
    *(uint4*)(dst + c0 * 8)     = x0;
    *(uint4*)(dst + c0 * 8 + 8) = x1;
  }
}

// ---------------------------------------------------------------------------
// Q/K/V projection as GEMM: [4096 x 1024] @ Wcat^T, 128x128 tile, BK=32.
// A raw (dual-dtype), B = wt (bf16, k-contiguous). Out [B][H][S][DH] bf16.
// grid (32, 8, 3), block 256 (4 waves, 2x2 quadrants of 64).
// ---------------------------------------------------------------------------
__global__ __launch_bounds__(256) void proj_kernel(
    const void* __restrict__ qin, const void* __restrict__ kin, const void* __restrict__ vin,
    const u16* __restrict__ wt, const u16* __restrict__ conv,
    const int* __restrict__ flag,
    u16* __restrict__ qo, u16* __restrict__ ko, u16* __restrict__ vo)
{
  const int z = blockIdx.z;
  const void* A   = (z == 0) ? qin : (z == 1) ? kin : vin;
  const u16* Wz   = wt + (size_t)z * (H_ * DH_ * HID_);
  const u16* bias = conv + ((z == 0) ? OFF_BQ : (z == 1) ? OFF_BK : OFF_BV);
  u16*       O    = (z == 0) ? qo : (z == 1) ? ko : vo;
  const int rt = blockIdx.x, ct = blockIdx.y;
  const int tid = threadIdx.x, lane = tid & 63, w = tid >> 6, quad = lane >> 4, l16 = lane & 15;
  const int isf = *flag;

  __shared__ __align__(16) u16 a_l[128 * 32];
  __shared__ __align__(16) u16 b_l[128 * 32];

  floatx4 acc[4][4];
  #pragma unroll
  for (int i = 0; i < 4; ++i)
    #pragma unroll
    for (int j = 0; j < 4; ++j) acc[i][j] = (floatx4){0.f,0.f,0.f,0.f};

  const int mq = (w & 1) * 64, nq = (w >> 1) * 64;

  for (int kk = 0; kk < 32; ++kk) {
    __syncthreads();
    #pragma unroll
    for (int i = 0; i < 2; ++i) {
      int idx = tid + 256 * i;
      int row = idx >> 2, c8 = (idx & 3) * 8;
      if (isf) {
        const float* Af = (const float*)A + (size_t)(rt * 128 + row) * HID_ + kk * 32 + c8;
        float4 v0 = *(const float4*)Af;
        float4 v1 = *(const float4*)(Af + 4);
        __align__(16) u16 tmp[8] = {f2bf(v0.x),f2bf(v0.y),f2bf(v0.z),f2bf(v0.w),
                                    f2bf(v1.x),f2bf(v1.y),f2bf(v1.z),f2bf(v1.w)};
        *(uint4*)(a_l + row * 32 + c8) = *(const uint4*)tmp;
      } else {
        *(uint4*)(a_l + row * 32 + c8) =
            *(const uint4*)((const u16*)A + (size_t)(rt * 128 + row) * HID_ + kk * 32 + c8);
      }
      *(uint4*)(b_l + row * 32 + c8) =
          *(const uint4*)(Wz + (size_t)(ct * 128 + row) * HID_ + kk * 32 + c8);
    }
    __syncthreads();
    short8 af[4], bfr[4];
    #pragma unroll
    for (int i = 0; i < 4; ++i) {
      af[i]  = *(const short8*)(a_l + (mq + i * 16 + l16) * 32 + quad * 8);
      bfr[i] = *(const short8*)(b_l + (nq + i * 16 + l16) * 32 + quad * 8);
    }
    #pragma unroll
    for (int i = 0; i < 4; ++i)
      #pragma unroll
      for (int j = 0; j < 4; ++j)
        acc[i][j] = mfma_bf16(af[i], bfr[j], acc[i][j]);
  }

  #pragma unroll
  for (int j = 0; j < 4; ++j) {
    int col = ct * 128 + nq + j * 16 + l16;
    int hh = col >> 6, e = col & 63;
    float bb = bf2f(bias[hh * 64 + e]);
    #pragma unroll
    for (int i = 0; i < 4; ++i) {
      #pragma unroll
      for (int r = 0; r < 4; ++r) {
        int m = rt * 128 + mq + i * 16 + quad * 4 + r;
        int bidx = m >> 10, srow = m & 1023;
        O[(((size_t)(bidx * H_ + hh)) * S_ + srow) * DH_ + e] = f2bf(acc[i][j][r] + bb);
      }
    }
  }
}

// ---------------------------------------------------------------------------
// Fused attention, q-tile 64 x k-tile 64, 16 k-steps, 2 barriers each.
// rel-k: RQ = Q @ relk^T via MFMA (preamble). rel-v: far tiles via indicator-
// column MFMA row-sums; near tiles (|dkt|<=1) via LDS buckets; epilogue
// rvb = Bfull @ relv via MFMA. grid (16, 16, 4), block 256.
// ---------------------------------------------------------------------------
__global__ __launch_bounds__(256) void attn_kernel(
    const u16* __restrict__ Q, const u16* __restrict__ K, const u16* __restrict__ V,
    const u16* __restrict__ conv, u16* __restrict__ Ox)
{
  const int qt = blockIdx.x, h = blockIdx.y, b = blockIdx.z;
  const int tid = threadIdx.x;
  const int lane = tid & 63, w = tid >> 6, quad = lane >> 4, l16 = lane & 15;
  const size_t base = ((size_t)(b * H_ + h)) * S_ * DH_;

  __shared__ __align__(16) char smem[52224];
  u16*   q_l    = (u16*)(smem);            // [64][72]
  u16*   k_l    = (u16*)(smem + 9216);     // [64][72]; epilogue: relv^T [64 e][72]
  u16*   vt_l   = (u16*)(smem + 18432);    // [64 e][72] (chunk-swizzled V^T)
  u16*   p_l    = (u16*)(smem + 27648);    // [64][72]; epilogue: Bfull bf16 [64][72]
  u16*   rq_l   = (u16*)(smem + 36864);    // [64][40] bf16
  float* bucket = (float*)(smem + 41984);  // [64][40]; preamble: relk_b u16 [48][72]
  u16*   rkb    = (u16*)(smem + 41984);

  // preamble: stage Q tile + relk (B-layout rows, zero-padded to 48)
  #pragma unroll
  for (int i = 0; i < 2; ++i) {
    int idx = tid + 256 * i;
    int row = idx >> 3, c8 = (idx & 7) * 8;
    *(uint4*)(q_l + row * 72 + c8) =
        *(const uint4*)(Q + base + (size_t)(qt * 64 + row) * DH_ + c8);
  }
  const u16* relk = conv + OFF_RELK;
  for (int idx = tid; idx < 48 * 8; idx += 256) {
    int row = idx >> 3, c8 = (idx & 7) * 8;
    uint4 v = make_uint4(0, 0, 0, 0);
    if (row < NDIST) v = *(const uint4*)(relk + row * 64 + c8);
    *(uint4*)(rkb + row * 72 + c8) = v;
  }
  __syncthreads();

  const int m0 = w * 16;
  short8 qa0 = *(const short8*)(q_l + (m0 + l16) * 72 + quad * 8);
  short8 qa1 = *(const short8*)(q_l + (m0 + l16) * 72 + 32 + quad * 8);

  // RQ[m][d] = q[m,:] . relk[d,:]
  #pragma unroll
  for (int t3 = 0; t3 < 3; ++t3) {
    floatx4 c = {0.f,0.f,0.f,0.f};
    c = mfma_bf16(qa0, *(const short8*)(rkb + (t3 * 16 + l16) * 72 + quad * 8), c);
    c = mfma_bf16(qa1, *(const short8*)(rkb + (t3 * 16 + l16) * 72 + 32 + quad * 8), c);
    int d = t3 * 16 + l16;
    if (d < NDIST) {
      #pragma unroll
      for (int r = 0; r < 4; ++r) rq_l[(m0 + quad * 4 + r) * 40 + d] = f2bf(c[r]);
    }
  }
  __syncthreads();              // relk_b reads done -> region becomes bucket
  for (int idx = tid; idx < 64 * 40; idx += 256) bucket[idx] = 0.f;

  floatx4 o[4], oi = {0.f,0.f,0.f,0.f};
  #pragma unroll
  for (int t = 0; t < 4; ++t) o[t] = (floatx4){0.f,0.f,0.f,0.f};

  for (int kt = 0; kt < 16; ++kt) {
    __syncthreads();            // prev iter LDS reads done (kt=0: bucket zero visible)
    #pragma unroll
    for (int i = 0; i < 2; ++i) {
      int idx = tid + 256 * i;
      int row = idx >> 3, c8 = (idx & 7) * 8;
      *(uint4*)(k_l + row * 72 + c8) =
          *(const uint4*)(K + base + (size_t)(kt * 64 + row) * DH_ + c8);
    }
    {
      int kcol = lane;          // lane = k: conflict-free swizzled scatter
      #pragma unroll
      for (int ph = 0; ph < 2; ++ph) {
        int e8 = w * 16 + ph * 8;
        uint4 vv = *(const uint4*)(V + base + (size_t)(kt * 64 + kcol) * DH_ + e8);
        const u16* t8 = (const u16*)&vv;
        #pragma unroll
        for (int j = 0; j < 8; ++j) {
          int e = e8 + j;
          vt_l[e * 72 + (((kcol >> 3) ^ (e & 7)) << 3) + (kcol & 7)] = t8[j];
        }
      }
    }
    __syncthreads();

    const int dkt = kt - qt;
    const bool near = (dkt >= -1) && (dkt <= 1);

    #pragma unroll
    for (int t = 0; t < 4; ++t) {
      floatx4 s = {0.f,0.f,0.f,0.f};
      s = mfma_bf16(qa0, *(const short8*)(k_l + (t * 16 + l16) * 72 + quad * 8), s);
      s = mfma_bf16(qa1, *(const short8*)(k_l + (t * 16 + l16) * 72 + 32 + quad * 8), s);
      int kcol = t * 16 + l16;
      #pragma unroll
      for (int r = 0; r < 4; ++r) {
        int m = m0 + quad * 4 + r;
        int delta = (kt * 64 + kcol) - (qt * 64 + m);
        int dist = (delta < -16 ? -16 : (delta > 16 ? 16 : delta)) + 16;
        float logit = (s[r] + bf2f(rq_l[m * 40 + dist])) * SCALE_;
        u16 pu = f2bf(__expf(fminf(logit, 30.f)));
        p_l[m * 72 + kcol] = pu;
        if (near) {
          float pv = bf2f(pu);
          float vhi = (dist == 32) ? pv : 0.f;
          float vlo = (dist == 0) ? pv : 0.f;
          #pragma unroll
          for (int off2 = 1; off2 < 16; off2 <<= 1) {
            vhi += __shfl_xor(vhi, off2, 16);
            vlo += __shfl_xor(vlo, off2, 16);
          }
          if (l16 == 0) {
            if (vhi != 0.f) atomicAdd(&bucket[m * 40 + 32], vhi);
            if (vlo != 0.f) atomicAdd(&bucket[m * 40 + 0], vlo);
          }
          if (dist > 0 && dist < 32) atomicAdd(&bucket[m * 40 + dist], pv);
        }
      }
    }

    // PV + far-tile indicator row-sums (same-wave P round-trip, no barrier)
    u16 iv = ((l16 == 0 && dkt <= -2) || (l16 == 1 && dkt >= 2)) ? (u16)0x3F80 : (u16)0;
    short8 ib;
    #pragma unroll
    for (int j = 0; j < 8; ++j) ib[j] = (short)iv;
    short8 pa0 = *(const short8*)(p_l + (m0 + l16) * 72 + quad * 8);
    short8 pa1 = *(const short8*)(p_l + (m0 + l16) * 72 + 32 + quad * 8);
    oi = mfma_bf16(pa0, ib, oi);
    oi = mfma_bf16(pa1, ib, oi);
    #pragma unroll
    for (int t = 0; t < 4; ++t) {
      int e = t * 16 + l16;
      short8 vb0 = *(const short8*)(vt_l + e * 72 + (((quad    ) ^ (e & 7)) << 3));
      short8 vb1 = *(const short8*)(vt_l + e * 72 + (((4 + quad) ^ (e & 7)) << 3));
      o[t] = mfma_bf16(pa0, vb0, o[t]);
      o[t] = mfma_bf16(pa1, vb1, o[t]);
    }
  }

  __syncthreads();              // loop LDS use + atomics done
  // fold far sums (s_lo at col0, s_hi at col1 of oi) into bucket
  if (l16 == 0) {
    #pragma unroll
    for (int r = 0; r < 4; ++r) bucket[(m0 + quad * 4 + r) * 40 + 0] += oi[r];
  } else if (l16 == 1) {
    #pragma unroll
    for (int r = 0; r < 4; ++r) bucket[(m0 + quad * 4 + r) * 40 + 32] += oi[r];
  }
  __syncthreads();

  u16* rvT = k_l;               // relv^T [64 e][72]
  u16* Bf  = p_l;               // Bfull bf16 [64 m][72]
  for (int idx = tid; idx < 576; idx += 256) {
    ((uint4*)rvT)[idx] = make_uint4(0, 0, 0, 0);
    ((uint4*)Bf)[idx]  = make_uint4(0, 0, 0, 0);
  }
  __syncthreads();
  const u16* relv = conv + OFF_RELV;
  for (int idx = tid; idx < NDIST * 64; idx += 256) {
    int d = idx >> 6, e = idx & 63;
    rvT[e * 72 + d] = relv[idx];
  }
  for (int idx = tid; idx < 64 * NDIST; idx += 256) {
    int m = idx / NDIST, d = idx - m * NDIST;
    Bf[m * 72 + d] = f2bf(bucket[m * 40 + d]);
  }
  __syncthreads();

  // o += Bfull @ relv
  short8 ba0 = *(const short8*)(Bf + (m0 + l16) * 72 + quad * 8);
  short8 ba1 = *(const short8*)(Bf + (m0 + l16) * 72 + 32 + quad * 8);
  #pragma unroll
  for (int t = 0; t < 4; ++t) {
    short8 rb0 = *(const short8*)(rvT + (t * 16 + l16) * 72 + quad * 8);
    short8 rb1 = *(const short8*)(rvT + (t * 16 + l16) * 72 + 32 + quad * 8);
    o[t] = mfma_bf16(ba0, rb0, o[t]);
    o[t] = mfma_bf16(ba1, rb1, o[t]);
  }

  float rl[4];
  #pragma unroll
  for (int r = 0; r < 4; ++r) {
    int m = m0 + quad * 4 + r;
    float s = 0.f;
    #pragma unroll
    for (int d = 0; d < NDIST; ++d) s += bucket[m * 40 + d];
    rl[r] = 1.f / s;
  }

  #pragma unroll
  for (int t = 0; t < 4; ++t) {
    int e = t * 16 + l16;
    #pragma unroll
    for (int r = 0; r < 4; ++r) {
      int srow = qt * 64 + m0 + quad * 4 + r;
      Ox[((size_t)(b * S_ + srow)) * HID_ + h * 64 + e] = f2bf(o[t][r] * rl[r]);
    }
  }
}

// ---------------------------------------------------------------------------
// fc: out = X @ fcW^T + b. X bf16 [4096][1024] (ws), fcW k-contiguous.
// 128x128 tile, BK=32. Dual-dtype output. grid (32, 8), block 256.
// ---------------------------------------------------------------------------
__global__ __launch_bounds__(256) void fc_kernel(
    const u16* __restrict__ X, const u16* __restrict__ conv,
    const int* __restrict__ flag, void* __restrict__ outv)
{
  const u16* Wf  = conv + OFF_FCW;
  const u16* bfc = conv + OFF_FCB;
  const int rt = blockIdx.x, ct = blockIdx.y;
  const int tid = threadIdx.x, lane = tid & 63, w = tid >> 6, quad = lane >> 4, l16 = lane & 15;
  const int isf = *flag;

  __shared__ __align__(16) u16 a_l[128 * 32];
  __shared__ __align__(16) u16 b_l[128 * 32];

  floatx4 acc[4][4];
  #pragma unroll
  for (int i = 0; i < 4; ++i)
    #pragma unroll
    for (int j = 0; j < 4; ++j) acc[i][j] = (floatx4){0.f,0.f,0.f,0.f};

  const int mq = (w & 1) * 64, nq = (w >> 1) * 64;

  for (int kk = 0; kk < 32; ++kk) {
    __syncthreads();
    #pragma unroll
    for (int i = 0; i < 2; ++i) {
      int idx = tid + 256 * i;
      int row = idx >> 2, c8 = (idx & 3) * 8;
      *(uint4*)(a_l + row * 32 + c8) =
          *(const uint4*)(X + (size_t)(rt * 128 + row) * HID_ + kk * 32 + c8);
      *(uint4*)(b_l + row * 32 + c8) =
          *(const uint4*)(Wf + (size_t)(ct * 128 + row) * HID_ + kk * 32 + c8);
    }
    __syncthreads();
    short8 af[4], bfr[4];
    #pragma unroll
    for (int i = 0; i < 4; ++i) {
      af[i]  = *(const short8*)(a_l + (mq + i * 16 + l16) * 32 + quad * 8);
      bfr[i] = *(const short8*)(b_l + (nq + i * 16 + l16) * 32 + quad * 8);
    }
    #pragma unroll
    for (int i = 0; i < 4; ++i)
      #pragma unroll
      for (int j = 0; j < 4; ++j)
        acc[i][j] = mfma_bf16(af[i], bfr[j], acc[i][j]);
  }

  #pragma unroll
  for (int j = 0; j < 4; ++j) {
    int col = ct * 128 + nq + j * 16 + l16;
    float bb = bf2f(bfc[col]);
    #pragma unroll
    for (int i = 0; i < 4; ++i) {
      #pragma unroll
      for (int r = 0; r < 4; ++r) {
        int m = rt * 128 + mq + i * 16 + quad * 4 + r;
        float val = acc[i][j][r] + bb;
        size_t idx = (size_t)m * HID_ + col;
        if (isf) ((float*)outv)[idx] = val;
        else     ((u16*)outv)[idx]   = f2bf(val);
      }
    }
  }
}

extern "C" void kernel_launch(void* const* d_in, const int* in_sizes, int n_in,
                              void* d_out, int out_size, void* d_ws, size_t ws_size,
                              hipStream_t stream) {
  int* flag = (int*)d_ws;
  u16* conv = (u16*)((char*)d_ws + 16);
  u16* wt   = conv + CONV_TOT;                 // 3*16*64*1024 = 3,145,728
  u16* qw   = wt + 3145728;
  u16* kw   = qw + 4194304;
  u16* vw   = kw + 4194304;
  u16* xw   = vw + 4194304;

  detect_kernel<<<1, 256, 0, stream>>>((const u16*)d_in[0], flag);

  SrcPtrs sp;
  sp.p[0] = d_in[4];  sp.p[1] = d_in[6];  sp.p[2] = d_in[8];
  sp.p[3] = d_in[9];  sp.p[4] = d_in[10]; sp.p[5] = d_in[11]; sp.p[6] = d_in[12];
  convert_kernel<<<1034, 256, 0, stream>>>(sp, flag, conv);

  wtrans_kernel<<<dim3(16, 16, 3), 256, 0, stream>>>(d_in[3], d_in[5], d_in[7], flag, wt);
  proj_kernel<<<dim3(32, 8, 3), 256, 0, stream>>>(d_in[0], d_in[1], d_in[2],
                                                  wt, conv, flag, qw, kw, vw);
  attn_kernel<<<dim3(16, 16, 4), 256, 0, stream>>>(qw, kw, vw, conv, xw);
  fc_kernel<<<dim3(32, 8), 256, 0, stream>>>(xw, conv, flag, (u16*)d_out);
}